// Round 8
// baseline (228.430 us; speedup 1.0000x reference)
//
#include <hip/hip_runtime.h>
#include <hip/hip_bf16.h>
#include <cstddef>

// Problem constants
#define BB 8
#define DIM 256
#define HH 48
#define WW 48
#define HW 2304        // 48*48
#define HEADS 8
#define DH 32
#define BH 64          // B*HEADS
#define HK 24
#define WK 24
#define NN 576         // HK*WK
#define SCALE 0.17677669529663687f
#define EPSF 1e-5f

typedef __attribute__((ext_vector_type(8))) short short8;
typedef __attribute__((ext_vector_type(4))) float f32x4;

static __device__ inline short f2bf_s(float f) {
  __hip_bfloat16 h = __float2bfloat16(f);
  return *reinterpret_cast<short*>(&h);
}

// pack two floats into bf16 pair (round-half-up): lo short = a, hi short = b
static __device__ inline unsigned pkrnd(float a, float b) {
  unsigned ua = __builtin_bit_cast(unsigned, a) + 0x8000u;
  unsigned ub = __builtin_bit_cast(unsigned, b) + 0x8000u;
  return __builtin_amdgcn_perm(ub, ua, 0x07060302);
}

// split 8 fp32 into bf16 hi/lo short8s (truncation split) -- bit-identical to
// the original plane split.
static __device__ inline void split8(const float* xf, short8& bh, short8& bl) {
  union { unsigned u[4]; short8 v; } H, L;
#pragma unroll
  for (int p = 0; p < 4; p++) {
    float x0 = xf[2 * p], x1 = xf[2 * p + 1];
    unsigned u0 = __builtin_bit_cast(unsigned, x0) & 0xffff0000u;
    unsigned u1 = __builtin_bit_cast(unsigned, x1) & 0xffff0000u;
    float l0 = x0 - __builtin_bit_cast(float, u0);
    float l1 = x1 - __builtin_bit_cast(float, u1);
    H.u[p] = __builtin_amdgcn_perm(u1, u0, 0x07060302);
    L.u[p] = __builtin_amdgcn_perm(__builtin_bit_cast(unsigned, l1),
                                   __builtin_bit_cast(unsigned, l0), 0x07060302);
  }
  bh = H.v;
  bl = L.v;
}

// ---------------------------------------------------------------------------
// q GEMM reading x and wq DIRECTLY (round-5 form, best measured). 512 thr.
// blocks [0,288): q GEMM, 8 waves x (32o x 64m). Per 128-c half: stage raw
//   x (128c x 64m fp32, coalesced) -> LDS, transpose+truncation-split into
//   swizzled bf16 hi/lo [64m][128c] half-tiles, MFMA. Half-1 raw staging is
//   issued before half-0's MFMA loop (overlap). W read fp32 + in-reg split8.
// blocks [288,1440): kv transpose into kvT fp32 (b, m, 256c) [in d_out].
// ---------------------------------------------------------------------------
__global__ __launch_bounds__(512) void gemm_q_fused(
    const float* __restrict__ wq, const float* __restrict__ bias,
    const float* __restrict__ x, float* __restrict__ Y,
    const float* __restrict__ kv, float* __restrict__ kvT) {
  __shared__ float sLDS[16384];          // 64 KB
  float* s_raw = sLDS;                   // [128][64] fp32 (32 KB)
  short* s_h   = (short*)(sLDS + 8192);  // [64][128] bf16 hi (16 KB)
  short* s_l   = ((short*)(sLDS + 8192)) + 8192;  // bf16 lo (16 KB)
  const int bid = blockIdx.x;
  const int tid = threadIdx.x;

  if (bid < 288) {
    const int b = bid / 36;
    const int mBase = (bid % 36) * 64;
    const int wave = tid >> 6, lane = tid & 63;
    const int quad = lane >> 4, l15 = lane & 15;
    const int oBase = wave * 32;
    const int cm = tid & 63, cg = tid >> 6;        // convert roles
    const int ck0 = cg * 2, ck1 = cg * 2 + 1;
    const int cvt0 = cm * 128 + ((ck0 ^ (cm & 7)) << 3);
    const int cvt1 = cm * 128 + ((ck1 ^ (cm & 7)) << 3);

    f32x4 acc[2][4] = {};

    // ---- stage raw half 0 ----
    {
      const float* xb = x + ((size_t)b * 256) * HW + mBase;
#pragma unroll
      for (int it = 0; it < 4; it++) {
        int u = it * 512 + tid;          // 0..2047
        int c = u >> 4, f4 = u & 15;
        *(float4*)(&s_raw[c * 64 + f4 * 4]) =
            *(const float4*)(xb + (size_t)c * HW + f4 * 4);
      }
    }
    __syncthreads();

    for (int half = 0; half < 2; half++) {
      // ---- convert: transpose + split into swizzled bf16 half-tile ----
      {
        float vals[16];
#pragma unroll
        for (int i = 0; i < 16; i++) vals[i] = s_raw[(cg * 16 + i) * 64 + cm];
        short8 h0, l0, h1, l1;
        split8(vals, h0, l0);
        split8(vals + 8, h1, l1);
        *(short8*)(&s_h[cvt0]) = h0;
        *(short8*)(&s_l[cvt0]) = l0;
        *(short8*)(&s_h[cvt1]) = h1;
        *(short8*)(&s_l[cvt1]) = l1;
      }
      __syncthreads();

      // ---- issue next half's raw staging (overlaps MFMA below) ----
      if (half == 0) {
        const float* xb = x + ((size_t)b * 256 + 128) * HW + mBase;
#pragma unroll
        for (int it = 0; it < 4; it++) {
          int u = it * 512 + tid;
          int c = u >> 4, f4 = u & 15;
          *(float4*)(&s_raw[c * 64 + f4 * 4]) =
              *(const float4*)(xb + (size_t)c * HW + f4 * 4);
        }
      }

      // ---- MFMA over this 128-c half ----
      for (int kc = 0; kc < 128; kc += 32) {
        short8 ah[2], al[2];
#pragma unroll
        for (int os = 0; os < 2; os++) {
          const float* wrow = wq + (size_t)(oBase + os * 16 + l15) * 256 +
                              half * 128 + kc + quad * 8;
          float w8[8];
          *(float4*)(w8) = *(const float4*)(wrow);
          *(float4*)(w8 + 4) = *(const float4*)(wrow + 4);
          split8(w8, ah[os], al[os]);
        }
#pragma unroll
        for (int mt = 0; mt < 4; mt++) {
          int row = mt * 16 + l15;
          int off = row * 128 + ((((kc >> 3) + quad) ^ (row & 7)) << 3);
          short8 bh_ = *(const short8*)(&s_h[off]);
          short8 bl_ = *(const short8*)(&s_l[off]);
#pragma unroll
          for (int os = 0; os < 2; os++) {
            acc[os][mt] = __builtin_amdgcn_mfma_f32_16x16x32_bf16(ah[os], bh_, acc[os][mt], 0, 0, 0);
            acc[os][mt] = __builtin_amdgcn_mfma_f32_16x16x32_bf16(al[os], bh_, acc[os][mt], 0, 0, 0);
            acc[os][mt] = __builtin_amdgcn_mfma_f32_16x16x32_bf16(ah[os], bl_, acc[os][mt], 0, 0, 0);
          }
        }
      }
      __syncthreads();   // protect s_h/s_l (and raw for half 1's convert)
    }

#pragma unroll
    for (int os = 0; os < 2; os++)
#pragma unroll
      for (int r = 0; r < 4; r++) {
        int o = oBase + os * 16 + quad * 4 + r;
        float bs = bias[o];
        float* yp = Y + ((size_t)b * 256 + o) * HW + mBase + l15;
#pragma unroll
        for (int mt = 0; mt < 4; mt++) yp[mt * 16] = acc[os][mt][r] + bs;
      }
  } else {
    // kv transpose (64x64 tile), 512 threads
    float* tf = sLDS;                  // [64][65]
    int bb = bid - 288;
    int mt = bb % 36, t2 = bb / 36;
    int ct = t2 & 3, b = t2 >> 2;
    const int c0 = ct * 64, m0 = mt * 64;
    const int col = tid & 63, row8 = tid >> 6;   // 0..7
    const float* xb = kv + ((size_t)b * 256 + c0) * HW + m0;
#pragma unroll
    for (int k = 0; k < 8; k++) {
      int c = row8 + k * 8;
      tf[c * 65 + col] = xb[(size_t)c * HW + col];
    }
    __syncthreads();
    float* ot = kvT + ((size_t)b * HW + m0) * 256 + c0;
#pragma unroll
    for (int k = 0; k < 8; k++) {
      int m = row8 + k * 8;
      ot[(size_t)m * 256 + col] = tf[col * 65 + m];
    }
  }
}

// ---------------------------------------------------------------------------
// dw conv + LN + GELU + offsets + bilinear sample, one thread per (n, ch).
// 256 threads = 8 n x 32 ch. Grid 4608 blocks, XCD-swizzled so bid%8 = b.
// q 5x20x32ch patch + all 800 dw weights staged in LDS; conv taps are
// conflict-free ds_read_b32. kvT (b, hw, 256c) fp32 -> coalesced taps.
// Writes kvsT bf16 hi/lo (b, n, 256c).
// ---------------------------------------------------------------------------
#define QPS 101   // per-channel LDS stride for q patch (5*20 + 1)
__global__ __launch_bounds__(256) void dw_sample_kernel(
    const float* __restrict__ q, const float* __restrict__ kvT,
    const float* __restrict__ w_dw, const float* __restrict__ b_dw,
    const float* __restrict__ ln_w, const float* __restrict__ ln_b,
    const float* __restrict__ w_off, short* __restrict__ kvsTh,
    short* __restrict__ kvsTl) {
  __shared__ float s_q[32 * QPS];   // [ch][5 rows][20 cols], stride QPS
  __shared__ float s_w[DH * 25];
  const int tid = threadIdx.x;
  const int ch = tid & 31;
  const int np = tid >> 5;
  const int bid = blockIdx.x;
  const int b = bid & 7;
  const int r = bid >> 3;
  const int head = r / 72;
  const int rr = r - head * 72;
  const int yk = rr / 3;
  const int xk0 = (rr - yk * 3) * 8;
  const int bh = b * 8 + head;
  const int xk = xk0 + np;
  const int n = yk * WK + xk;

  for (int i = tid; i < DH * 25; i += 256) s_w[i] = w_dw[i];

  {
    const int y0 = yk * 2 - 2, x0 = xk0 * 2 - 2;
    const float* qbh = q + (size_t)bh * DH * HW;
#pragma unroll
    for (int it = 0; it < 13; it++) {
      int e = it * 256 + tid;
      if (e < 3200) {
        int c = e / 100;
        int rem = e - c * 100;
        int dy = rem / 20;
        int xl = rem - dy * 20;
        int gy = y0 + dy, gx = x0 + xl;
        float v = 0.f;
        if ((unsigned)gy < HH && (unsigned)gx < WW)
          v = qbh[(size_t)c * HW + gy * WW + gx];
        s_q[c * QPS + dy * 20 + xl] = v;
      }
    }
  }
  __syncthreads();

  float t = b_dw[ch];
  {
    const float* wp = s_w + ch * 25;
    const float* qp = s_q + ch * QPS + np * 2;
#pragma unroll
    for (int dy = 0; dy < 5; dy++)
#pragma unroll
      for (int dx = 0; dx < 5; dx++)
        t += wp[dy * 5 + dx] * qp[dy * 20 + dx];
  }

  float mu = t;
#pragma unroll
  for (int m = 1; m < 32; m <<= 1) mu += __shfl_xor(mu, m);
  mu *= (1.0f / DH);
  float d = t - mu;
  float var = d * d;
#pragma unroll
  for (int m = 1; m < 32; m <<= 1) var += __shfl_xor(var, m);
  var *= (1.0f / DH);
  float rstd = rsqrtf(var + EPSF);

  float xn = d * rstd * ln_w[ch] + ln_b[ch];
  float g = 0.5f * xn * (1.0f + erff(xn * 0.70710678118654752f));
  float o0 = w_off[ch] * g;
  float o1 = w_off[DH + ch] * g;
#pragma unroll
  for (int m = 1; m < 32; m <<= 1) {
    o0 += __shfl_xor(o0, m);
    o1 += __shfl_xor(o1, m);
  }

  const float ref_y = (0.5f + (float)yk) / 23.0f * 2.0f - 1.0f;
  const float ref_x = (0.5f + (float)xk) / 23.0f * 2.0f - 1.0f;
  float py = fminf(fmaxf(o0 + ref_y, -1.0f), 1.0f);
  float px = fminf(fmaxf(o1 + ref_x, -1.0f), 1.0f);

  float gx = (px + 1.0f) * 0.5f * 47.0f;
  float gy = (py + 1.0f) * 0.5f * 47.0f;
  float x0f = floorf(gx), y0f = floorf(gy);
  float wx = gx - x0f, wy = gy - y0f;
  int x0 = (int)x0f, y0 = (int)y0f;
  int x0i = min(max(x0, 0), WW - 1);
  int x1i = min(max(x0 + 1, 0), WW - 1);
  int y0i = min(max(y0, 0), HH - 1);
  int y1i = min(max(y0 + 1, 0), HH - 1);
  float w00 = (1.f - wx) * (1.f - wy);
  float w01 = wx * (1.f - wy);
  float w10 = (1.f - wx) * wy;
  float w11 = wx * wy;

  const float* kvb = kvT + (size_t)b * HW * 256 + head * DH + ch;
  float val = w00 * kvb[(size_t)(y0i * WW + x0i) * 256]
            + w01 * kvb[(size_t)(y0i * WW + x1i) * 256]
            + w10 * kvb[(size_t)(y1i * WW + x0i) * 256]
            + w11 * kvb[(size_t)(y1i * WW + x1i) * 256];

  unsigned ub = __builtin_bit_cast(unsigned, val);
  unsigned uh = ub & 0xffff0000u;
  float rem = val - __builtin_bit_cast(float, uh);
  size_t idx = ((size_t)b * NN + n) * 256 + head * DH + ch;
  kvsTh[idx] = (short)(uh >> 16);
  kvsTl[idx] = (short)(__builtin_bit_cast(unsigned, rem) >> 16);
}

// ---------------------------------------------------------------------------
// Fused K/V GEMM from kvsT (b,n,256) hi/lo; W read fp32 + in-reg split8.
// mode = blockIdx.y>>2: 0 -> K^T (b,n,256o); 1 -> V (b,256o,n).
// Grid (9, 8, 8), 256 threads.
// ---------------------------------------------------------------------------
__global__ __launch_bounds__(256) void kv_gemm_mfma(
    const float* __restrict__ wk, const float* __restrict__ bk,
    const float* __restrict__ wv, const float* __restrict__ bv,
    const short* __restrict__ Xh, const short* __restrict__ Xl,
    short* __restrict__ Kb, short* __restrict__ Vb) {
  const int tid = threadIdx.x;
  const int wave = tid >> 6;
  const int lane = tid & 63;
  const int quad = lane >> 4, l15 = lane & 15;
  const int b = blockIdx.z;
  const int mode = blockIdx.y >> 2;
  const int oTile = (blockIdx.y & 3) * 64;
  const int nBase = blockIdx.x * 64;

  if (mode == 0) {
    const int nW = nBase + wave * 16;
    const short* arh = Xh + ((size_t)b * NN + nW + l15) * 256 + quad * 8;
    const short* arl = Xl + ((size_t)b * NN + nW + l15) * 256 + quad * 8;
    f32x4 acc[4] = {};
    for (int kc = 0; kc < 256; kc += 32) {
      short8 ah = *(const short8*)(arh + kc);
      short8 al = *(const short8*)(arl + kc);
#pragma unroll
      for (int ot = 0; ot < 4; ot++) {
        const float* wrow = wk + (size_t)(oTile + ot * 16 + l15) * 256 + kc + quad * 8;
        float w8[8];
        *(float4*)(w8) = *(const float4*)(wrow);
        *(float4*)(w8 + 4) = *(const float4*)(wrow + 4);
        short8 bh_, bl_;
        split8(w8, bh_, bl_);
        acc[ot] = __builtin_amdgcn_mfma_f32_16x16x32_bf16(ah, bh_, acc[ot], 0, 0, 0);
        acc[ot] = __builtin_amdgcn_mfma_f32_16x16x32_bf16(al, bh_, acc[ot], 0, 0, 0);
        acc[ot] = __builtin_amdgcn_mfma_f32_16x16x32_bf16(ah, bl_, acc[ot], 0, 0, 0);
      }
    }
    float bs[4];
#pragma unroll
    for (int ot = 0; ot < 4; ot++) bs[ot] = bk[oTile + ot * 16 + l15];
#pragma unroll
    for (int r = 0; r < 4; r++) {
      short* yp = Kb + ((size_t)b * NN + nW + quad * 4 + r) * 256 + oTile + l15;
#pragma unroll
      for (int ot = 0; ot < 4; ot++) yp[ot * 16] = f2bf_s(acc[ot][r] + bs[ot]);
    }
  } else {
    const int oW = oTile + wave * 16;
    const float* wrow = wv + (size_t)(oW + l15) * 256 + quad * 8;
    f32x4 acc[4] = {};
    for (int kc = 0; kc < 256; kc += 32) {
      float w8[8];
      *(float4*)(w8) = *(const float4*)(wrow + kc);
      *(float4*)(w8 + 4) = *(const float4*)(wrow + kc + 4);
      short8 ah, al;
      split8(w8, ah, al);
#pragma unroll
      for (int nt = 0; nt < 4; nt++) {
        short8 bh_ = *(const short8*)(Xh + ((size_t)b * NN + nBase + nt * 16 + l15) * 256 + kc + quad * 8);
        short8 bl_ = *(const short8*)(Xl + ((size_t)b * NN + nBase + nt * 16 + l15) * 256 + kc + quad * 8);
        acc[nt] = __builtin_amdgcn_mfma_f32_16x16x32_bf16(ah, bh_, acc[nt], 0, 0, 0);
        acc[nt] = __builtin_amdgcn_mfma_f32_16x16x32_bf16(al, bh_, acc[nt], 0, 0, 0);
        acc[nt] = __builtin_amdgcn_mfma_f32_16x16x32_bf16(ah, bl_, acc[nt], 0, 0, 0);
      }
    }
#pragma unroll
    for (int r = 0; r < 4; r++) {
      int o = oW + quad * 4 + r;
      float bs = bv[o];
      short* yp = Vb + ((size_t)b * 256 + o) * NN + nBase + l15;
#pragma unroll
      for (int nt = 0; nt < 4; nt++) yp[nt * 16] = f2bf_s(acc[nt][r] + bs);
    }
  }
}

// ---------------------------------------------------------------------------
// MFMA attention v9: denominator via in-register shuffle reduction (removes
// the ones-MFMA -- 20% of MFMA issue); otherwise round-5 structure:
// block-cooperative K/V LDS staging (double-buffered, 1 barrier/stage),
// mt=2 per wave, fixed-swizzle P transpose. Grid (18, 64), 256 threads.
// ---------------------------------------------------------------------------
__global__ __launch_bounds__(256) void attn_mfma(const float* __restrict__ q,
                                                 const short* __restrict__ Kb,
                                                 const short* __restrict__ Vb,
                                                 short* __restrict__ O) {
  __shared__ short sK[2][64 * 40];    // row stride 40 shorts (80 B)
  __shared__ short sV[2][32 * 88];    // row stride 88 shorts (176 B)
  __shared__ int sP[4][2][256];       // per-wave P transpose buffers
  const int tid = threadIdx.x;
  const int wave = tid >> 6;
  const int lane = tid & 63;
  const int quad = lane >> 4;
  const int l15 = lane & 15;
  const int bh = blockIdx.y;
  const int b = bh >> 3, head = bh & 7;
  const int mBase = blockIdx.x * 128 + wave * 32;

  short8 bq[2];
#pragma unroll
  for (int mt = 0; mt < 2; mt++) {
    const float* qp = q + ((size_t)bh * DH + quad * 8) * HW + mBase + mt * 16 + l15;
    short8 v;
#pragma unroll
    for (int j = 0; j < 8; j++) v[j] = f2bf_s(qp[(size_t)j * HW] * SCALE);
    bq[mt] = v;
  }

  const int kn = tid >> 2, kc = (tid & 3) * 8;
  const int vc = tid >> 3, vn = (tid & 7) * 8;
  const short* kg = Kb + (size_t)b * NN * 256 + head * DH;
  const short* vg = Vb + ((size_t)b * 256 + head * DH) * NN;

  short8 kreg = *(const short8*)(kg + (size_t)kn * 256 + kc);
  short8 vreg = *(const short8*)(vg + (size_t)vc * NN + vn);
  *(short8*)(&sK[0][kn * 40 + kc]) = kreg;
  *(short8*)(&sV[0][vc * 88 + vn]) = vreg;
  __syncthreads();

  const int g = (l15 >> 1) & 3;
  const int row16 = l15 * 16;
  const int wr0 = row16 + (((quad >> 1) ^ g) << 2) + ((quad & 1) << 1);
  const int wr1 = row16 + (((2 + (quad >> 1)) ^ g) << 2) + ((quad & 1) << 1);
  const int rd = row16 + ((quad ^ g) << 2);

  f32x4 oacc[2][2] = {};
  float dsum[2] = {0.f, 0.f};   // per-lane: row-sum of P for m = l15 (+mt*16)

  for (int s = 0; s < 9; s++) {
    const int buf = s & 1;
    if (s + 1 < 9) {
      kreg = *(const short8*)(kg + (size_t)((s + 1) * 64 + kn) * 256 + kc);
      vreg = *(const short8*)(vg + (size_t)vc * NN + (s + 1) * 64 + vn);
    }
#pragma unroll
    for (int nt = 0; nt < 2; nt++) {
      short8 ka0 = *(const short8*)(&sK[buf][(nt * 32 + l15) * 40 + quad * 8]);
      short8 ka1 = *(const short8*)(&sK[buf][(nt * 32 + 16 + l15) * 40 + quad * 8]);
      short8 va0 = *(const short8*)(&sV[buf][l15 * 88 + nt * 32 + quad * 8]);
      short8 va1 = *(const short8*)(&sV[buf][(16 + l15) * 88 + nt * 32 + quad * 8]);
      f32x4 z = {0.f, 0.f, 0.f, 0.f};
      f32x4 st[2][2];
      st[0][0] = __builtin_amdgcn_mfma_f32_16x16x32_bf16(ka0, bq[0], z, 0, 0, 0);
      st[0][1] = __builtin_amdgcn_mfma_f32_16x16x32_bf16(ka1, bq[0], z, 0, 0, 0);
      st[1][0] = __builtin_amdgcn_mfma_f32_16x16x32_bf16(ka0, bq[1], z, 0, 0, 0);
      st[1][1] = __builtin_amdgcn_mfma_f32_16x16x32_bf16(ka1, bq[1], z, 0, 0, 0);
#pragma unroll
      for (int mt = 0; mt < 2; mt++) {
        float p0 = __expf(st[mt][0][0]), p1 = __expf(st[mt][0][1]);
        float p2 = __expf(st[mt][0][2]), p3 = __expf(st[mt][0][3]);
        float p4 = __expf(st[mt][1][0]), p5 = __expf(st[mt][1][1]);
        float p6 = __expf(st[mt][1][2]), p7 = __expf(st[mt][1][3]);
        // denominator: row-sum over this nt's 32 n (lane's 8 + cross-quad)
        float ssum = ((p0 + p1) + (p2 + p3)) + ((p4 + p5) + (p6 + p7));
        ssum += __shfl_xor(ssum, 16);
        ssum += __shfl_xor(ssum, 32);
        dsum[mt] += ssum;
        int* base = &sP[wave][mt][0];
        *(int2*)(base + wr0) = make_int2((int)pkrnd(p0, p1), (int)pkrnd(p2, p3));
        *(int2*)(base + wr1) = make_int2((int)pkrnd(p4, p5), (int)pkrnd(p6, p7));
      }
#pragma unroll
      for (int mt = 0; mt < 2; mt++) {
        short8 pa = *(short8*)(&sP[wave][mt][0] + rd);
        oacc[mt][0] = __builtin_amdgcn_mfma_f32_16x16x32_bf16(pa, va0, oacc[mt][0], 0, 0, 0);
        oacc[mt][1] = __builtin_amdgcn_mfma_f32_16x16x32_bf16(pa, va1, oacc[mt][1], 0, 0, 0);
      }
    }
    if (s + 1 < 9) {
      *(short8*)(&sK[buf ^ 1][kn * 40 + kc]) = kreg;
      *(short8*)(&sV[buf ^ 1][vc * 88 + vn]) = vreg;
    }
    __syncthreads();
  }

#pragma unroll
  for (int mt = 0; mt < 2; mt++) {
    short* ob = O + ((size_t)b * HW + mBase + mt * 16) * 256 + head * DH + l15;
#pragma unroll
    for (int r = 0; r < 4; r++) {
      // dsum is indexed by m = l15; output rows are m = quad*4 + r.
      float den = __shfl(dsum[mt], quad * 4 + r);
      float inv = 1.0f / den;
      ob[(size_t)(quad * 4 + r) * 256] = f2bf_s(oacc[mt][0][r] * inv);
      ob[(size_t)(quad * 4 + r) * 256 + 16] = f2bf_s(oacc[mt][1][r] * inv);
    }
  }
}

// ---------------------------------------------------------------------------
// wo GEMM (round-5 form): 512 threads, 8 waves x (32o x 64m), X tile staged
// in 32KB LDS (chunk-XOR swizzle); W read fp32 + in-reg split8. Grid (36, 8).
// ---------------------------------------------------------------------------
__global__ __launch_bounds__(512) void wo_gemm_mfma(const float* __restrict__ wo,
                                                    const float* __restrict__ bias,
                                                    const short* __restrict__ X,
                                                    float* __restrict__ Y) {
  __shared__ short sX[64 * 256];   // 32 KB
  const int tid = threadIdx.x;
  const int b = blockIdx.y;
  const int mBase = blockIdx.x * 64;

  const short* src = X + ((size_t)b * HW + mBase) * 256;
#pragma unroll
  for (int it = 0; it < 4; it++) {
    int idx = it * 512 + tid;        // 0..2047
    int row = idx >> 5, ck = idx & 31;
    *(short8*)(&sX[row * 256 + ((ck ^ (row & 7)) << 3)]) =
        *(const short8*)(src + (size_t)row * 256 + ck * 8);
  }
  __syncthreads();

  const int wave = tid >> 6, lane = tid & 63;
  const int quad = lane >> 4, l15 = lane & 15;
  const int oBase = wave * 32;

  f32x4 acc[2][4] = {};
  for (int kc = 0; kc < 256; kc += 32) {
    short8 ah[2], al[2];
#pragma unroll
    for (int os = 0; os < 2; os++) {
      const float* wrow = wo + (size_t)(oBase + os * 16 + l15) * 256 + kc + quad * 8;
      float w8[8];
      *(float4*)(w8) = *(const float4*)(wrow);
      *(float4*)(w8 + 4) = *(const float4*)(wrow + 4);
      split8(w8, ah[os], al[os]);
    }
#pragma unroll
    for (int mt = 0; mt < 4; mt++) {
      int row = mt * 16 + l15;
      short8 bx = *(const short8*)(&sX[row * 256 + ((((kc >> 3) + quad) ^ (row & 7)) << 3)]);
#pragma unroll
      for (int os = 0; os < 2; os++) {
        acc[os][mt] = __builtin_amdgcn_mfma_f32_16x16x32_bf16(ah[os], bx, acc[os][mt], 0, 0, 0);
        acc[os][mt] = __builtin_amdgcn_mfma_f32_16x16x32_bf16(al[os], bx, acc[os][mt], 0, 0, 0);
      }
    }
  }

#pragma unroll
  for (int os = 0; os < 2; os++)
#pragma unroll
    for (int r = 0; r < 4; r++) {
      int o = oBase + os * 16 + quad * 4 + r;
      float bs = bias[o];
      float* yp = Y + ((size_t)b * 256 + o) * HW + mBase + l15;
#pragma unroll
      for (int mt = 0; mt < 4; mt++) yp[mt * 16] = acc[os][mt][r] + bs;
    }
}

// ---------------------------------------------------------------------------
extern "C" void kernel_launch(void* const* d_in, const int* in_sizes, int n_in,
                              void* d_out, int out_size, void* d_ws, size_t ws_size,
                              hipStream_t stream) {
  const float* x    = (const float*)d_in[0];
  const float* kv   = (const float*)d_in[1];
  const float* wq   = (const float*)d_in[2];
  const float* bq   = (const float*)d_in[3];
  const float* wk   = (const float*)d_in[4];
  const float* bk   = (const float*)d_in[5];
  const float* wv   = (const float*)d_in[6];
  const float* bv   = (const float*)d_in[7];
  const float* w_dw = (const float*)d_in[8];
  const float* b_dw = (const float*)d_in[9];
  const float* ln_w = (const float*)d_in[10];
  const float* ln_b = (const float*)d_in[11];
  const float* w_off= (const float*)d_in[12];
  const float* wo   = (const float*)d_in[13];
  const float* bo   = (const float*)d_in[14];
  float* out = (float*)d_out;
  float* ws = (float*)d_ws;

  // workspace (float slots), lifetimes:
  //   q     [0,        4718592)  fp32, born gemm_q, read by dw_sample + attn
  //   O     [4718592,  7077888)  bf16, born attn, read by wo
  //   kvsTh [7077888,  7667712), kvsTl [7667712, 8257536)  born dw
  //   Kb    [8257536,  8847360), Vb    [8847360, 9437184)  born kv_gemm
  // kvT (fp32, (b,hw,256)) lives in d_out: written by gemm_q_fused's
  // transpose blocks, read by dw_sample, overwritten at the end by wo_gemm.
  float* q     = ws;
  short* O     = (short*)(ws + 4718592);
  short* kvsTh = (short*)(ws + 7077888);
  short* kvsTl = (short*)(ws + 7667712);
  short* Kb    = (short*)(ws + 8257536);
  short* Vb    = (short*)(ws + 8847360);
  float* kvT = out;

  gemm_q_fused<<<dim3(1440), dim3(512), 0, stream>>>(wq, bq, x, q, kv, kvT);
  dw_sample_kernel<<<dim3(BH * NN / 8), dim3(256), 0, stream>>>(
      q, kvT, w_dw, b_dw, ln_w, ln_b, w_off, kvsTh, kvsTl);
  kv_gemm_mfma<<<dim3(NN / 64, 8, BB), dim3(256), 0, stream>>>(
      wk, bk, wv, bv, kvsTh, kvsTl, Kb, Vb);
  attn_mfma<<<dim3(HW / 128, BH), dim3(256), 0, stream>>>(q, Kb, Vb, O);
  wo_gemm_mfma<<<dim3(HW / 64, BB), dim3(512), 0, stream>>>(wo, bo, O, out);
}

// Round 9
// 221.261 us; speedup vs baseline: 1.0324x; 1.0324x over previous
//
#include <hip/hip_runtime.h>
#include <hip/hip_bf16.h>
#include <cstddef>

// Problem constants
#define BB 8
#define DIM 256
#define HH 48
#define WW 48
#define HW 2304        // 48*48
#define HEADS 8
#define DH 32
#define BH 64          // B*HEADS
#define HK 24
#define WK 24
#define NN 576         // HK*WK
#define SCALE 0.17677669529663687f
#define EPSF 1e-5f

typedef __attribute__((ext_vector_type(8))) short short8;
typedef __attribute__((ext_vector_type(4))) float f32x4;

static __device__ inline short f2bf_s(float f) {
  __hip_bfloat16 h = __float2bfloat16(f);
  return *reinterpret_cast<short*>(&h);
}

// pack two floats into bf16 pair (round-half-up): lo short = a, hi short = b
static __device__ inline unsigned pkrnd(float a, float b) {
  unsigned ua = __builtin_bit_cast(unsigned, a) + 0x8000u;
  unsigned ub = __builtin_bit_cast(unsigned, b) + 0x8000u;
  return __builtin_amdgcn_perm(ub, ua, 0x07060302);
}

// split 8 fp32 into bf16 hi/lo short8s (truncation split) -- bit-identical to
// the original plane split.
static __device__ inline void split8(const float* xf, short8& bh, short8& bl) {
  union { unsigned u[4]; short8 v; } H, L;
#pragma unroll
  for (int p = 0; p < 4; p++) {
    float x0 = xf[2 * p], x1 = xf[2 * p + 1];
    unsigned u0 = __builtin_bit_cast(unsigned, x0) & 0xffff0000u;
    unsigned u1 = __builtin_bit_cast(unsigned, x1) & 0xffff0000u;
    float l0 = x0 - __builtin_bit_cast(float, u0);
    float l1 = x1 - __builtin_bit_cast(float, u1);
    H.u[p] = __builtin_amdgcn_perm(u1, u0, 0x07060302);
    L.u[p] = __builtin_amdgcn_perm(__builtin_bit_cast(unsigned, l1),
                                   __builtin_bit_cast(unsigned, l0), 0x07060302);
  }
  bh = H.v;
  bl = L.v;
}

// ---------------------------------------------------------------------------
// q GEMM reading x and wq DIRECTLY (round-5 form, best measured). 512 thr.
// blocks [0,288): q GEMM, 8 waves x (32o x 64m). Per 128-c half: stage raw
//   x (128c x 64m fp32, coalesced) -> LDS, transpose+truncation-split into
//   swizzled bf16 hi/lo [64m][128c] half-tiles, MFMA. Half-1 raw staging is
//   issued before half-0's MFMA loop (overlap). W read fp32 + in-reg split8.
// blocks [288,1440): kv transpose into kvT fp32 (b, m, 256c) [in d_out].
// ---------------------------------------------------------------------------
__global__ __launch_bounds__(512) void gemm_q_fused(
    const float* __restrict__ wq, const float* __restrict__ bias,
    const float* __restrict__ x, float* __restrict__ Y,
    const float* __restrict__ kv, float* __restrict__ kvT) {
  __shared__ float sLDS[16384];          // 64 KB
  float* s_raw = sLDS;                   // [128][64] fp32 (32 KB)
  short* s_h   = (short*)(sLDS + 8192);  // [64][128] bf16 hi (16 KB)
  short* s_l   = ((short*)(sLDS + 8192)) + 8192;  // bf16 lo (16 KB)
  const int bid = blockIdx.x;
  const int tid = threadIdx.x;

  if (bid < 288) {
    const int b = bid / 36;
    const int mBase = (bid % 36) * 64;
    const int wave = tid >> 6, lane = tid & 63;
    const int quad = lane >> 4, l15 = lane & 15;
    const int oBase = wave * 32;
    const int cm = tid & 63, cg = tid >> 6;        // convert roles
    const int ck0 = cg * 2, ck1 = cg * 2 + 1;
    const int cvt0 = cm * 128 + ((ck0 ^ (cm & 7)) << 3);
    const int cvt1 = cm * 128 + ((ck1 ^ (cm & 7)) << 3);

    f32x4 acc[2][4] = {};

    // ---- stage raw half 0 ----
    {
      const float* xb = x + ((size_t)b * 256) * HW + mBase;
#pragma unroll
      for (int it = 0; it < 4; it++) {
        int u = it * 512 + tid;          // 0..2047
        int c = u >> 4, f4 = u & 15;
        *(float4*)(&s_raw[c * 64 + f4 * 4]) =
            *(const float4*)(xb + (size_t)c * HW + f4 * 4);
      }
    }
    __syncthreads();

    for (int half = 0; half < 2; half++) {
      // ---- convert: transpose + split into swizzled bf16 half-tile ----
      {
        float vals[16];
#pragma unroll
        for (int i = 0; i < 16; i++) vals[i] = s_raw[(cg * 16 + i) * 64 + cm];
        short8 h0, l0, h1, l1;
        split8(vals, h0, l0);
        split8(vals + 8, h1, l1);
        *(short8*)(&s_h[cvt0]) = h0;
        *(short8*)(&s_l[cvt0]) = l0;
        *(short8*)(&s_h[cvt1]) = h1;
        *(short8*)(&s_l[cvt1]) = l1;
      }
      __syncthreads();

      // ---- issue next half's raw staging (overlaps MFMA below) ----
      if (half == 0) {
        const float* xb = x + ((size_t)b * 256 + 128) * HW + mBase;
#pragma unroll
        for (int it = 0; it < 4; it++) {
          int u = it * 512 + tid;
          int c = u >> 4, f4 = u & 15;
          *(float4*)(&s_raw[c * 64 + f4 * 4]) =
              *(const float4*)(xb + (size_t)c * HW + f4 * 4);
        }
      }

      // ---- MFMA over this 128-c half ----
#pragma unroll
      for (int kc = 0; kc < 128; kc += 32) {
        short8 ah[2], al[2];
#pragma unroll
        for (int os = 0; os < 2; os++) {
          const float* wrow = wq + (size_t)(oBase + os * 16 + l15) * 256 +
                              half * 128 + kc + quad * 8;
          float w8[8];
          *(float4*)(w8) = *(const float4*)(wrow);
          *(float4*)(w8 + 4) = *(const float4*)(wrow + 4);
          split8(w8, ah[os], al[os]);
        }
#pragma unroll
        for (int mt = 0; mt < 4; mt++) {
          int row = mt * 16 + l15;
          int off = row * 128 + ((((kc >> 3) + quad) ^ (row & 7)) << 3);
          short8 bh_ = *(const short8*)(&s_h[off]);
          short8 bl_ = *(const short8*)(&s_l[off]);
#pragma unroll
          for (int os = 0; os < 2; os++) {
            acc[os][mt] = __builtin_amdgcn_mfma_f32_16x16x32_bf16(ah[os], bh_, acc[os][mt], 0, 0, 0);
            acc[os][mt] = __builtin_amdgcn_mfma_f32_16x16x32_bf16(al[os], bh_, acc[os][mt], 0, 0, 0);
            acc[os][mt] = __builtin_amdgcn_mfma_f32_16x16x32_bf16(ah[os], bl_, acc[os][mt], 0, 0, 0);
          }
        }
      }
      __syncthreads();   // protect s_h/s_l (and raw for half 1's convert)
    }

#pragma unroll
    for (int os = 0; os < 2; os++)
#pragma unroll
      for (int r = 0; r < 4; r++) {
        int o = oBase + os * 16 + quad * 4 + r;
        float bs = bias[o];
        float* yp = Y + ((size_t)b * 256 + o) * HW + mBase + l15;
#pragma unroll
        for (int mt = 0; mt < 4; mt++) yp[mt * 16] = acc[os][mt][r] + bs;
      }
  } else {
    // kv transpose (64x64 tile), 512 threads
    float* tf = sLDS;                  // [64][65]
    int bb = bid - 288;
    int mt = bb % 36, t2 = bb / 36;
    int ct = t2 & 3, b = t2 >> 2;
    const int c0 = ct * 64, m0 = mt * 64;
    const int col = tid & 63, row8 = tid >> 6;   // 0..7
    const float* xb = kv + ((size_t)b * 256 + c0) * HW + m0;
#pragma unroll
    for (int k = 0; k < 8; k++) {
      int c = row8 + k * 8;
      tf[c * 65 + col] = xb[(size_t)c * HW + col];
    }
    __syncthreads();
    float* ot = kvT + ((size_t)b * HW + m0) * 256 + c0;
#pragma unroll
    for (int k = 0; k < 8; k++) {
      int m = row8 + k * 8;
      ot[(size_t)m * 256 + col] = tf[col * 65 + m];
    }
  }
}

// ---------------------------------------------------------------------------
// dw conv + LN + GELU + offsets + bilinear sample, one thread per (n, ch).
// 256 threads = 8 n x 32 ch. Grid 4608 blocks, XCD-swizzled so bid%8 = b.
// q 5x20x32ch patch + all 800 dw weights staged in LDS; conv taps are
// conflict-free ds_read_b32. kvT (b, hw, 256c) fp32 -> coalesced taps.
// Writes kvsT bf16 hi/lo (b, n, 256c).
// ---------------------------------------------------------------------------
#define QPS 101   // per-channel LDS stride for q patch (5*20 + 1)
__global__ __launch_bounds__(256) void dw_sample_kernel(
    const float* __restrict__ q, const float* __restrict__ kvT,
    const float* __restrict__ w_dw, const float* __restrict__ b_dw,
    const float* __restrict__ ln_w, const float* __restrict__ ln_b,
    const float* __restrict__ w_off, short* __restrict__ kvsTh,
    short* __restrict__ kvsTl) {
  __shared__ float s_q[32 * QPS];   // [ch][5 rows][20 cols], stride QPS
  __shared__ float s_w[DH * 25];
  const int tid = threadIdx.x;
  const int ch = tid & 31;
  const int np = tid >> 5;
  const int bid = blockIdx.x;
  const int b = bid & 7;
  const int r = bid >> 3;
  const int head = r / 72;
  const int rr = r - head * 72;
  const int yk = rr / 3;
  const int xk0 = (rr - yk * 3) * 8;
  const int bh = b * 8 + head;
  const int xk = xk0 + np;
  const int n = yk * WK + xk;

  for (int i = tid; i < DH * 25; i += 256) s_w[i] = w_dw[i];

  {
    const int y0 = yk * 2 - 2, x0 = xk0 * 2 - 2;
    const float* qbh = q + (size_t)bh * DH * HW;
#pragma unroll
    for (int it = 0; it < 13; it++) {
      int e = it * 256 + tid;
      if (e < 3200) {
        int c = e / 100;
        int rem = e - c * 100;
        int dy = rem / 20;
        int xl = rem - dy * 20;
        int gy = y0 + dy, gx = x0 + xl;
        float v = 0.f;
        if ((unsigned)gy < HH && (unsigned)gx < WW)
          v = qbh[(size_t)c * HW + gy * WW + gx];
        s_q[c * QPS + dy * 20 + xl] = v;
      }
    }
  }
  __syncthreads();

  float t = b_dw[ch];
  {
    const float* wp = s_w + ch * 25;
    const float* qp = s_q + ch * QPS + np * 2;
#pragma unroll
    for (int dy = 0; dy < 5; dy++)
#pragma unroll
      for (int dx = 0; dx < 5; dx++)
        t += wp[dy * 5 + dx] * qp[dy * 20 + dx];
  }

  float mu = t;
#pragma unroll
  for (int m = 1; m < 32; m <<= 1) mu += __shfl_xor(mu, m);
  mu *= (1.0f / DH);
  float d = t - mu;
  float var = d * d;
#pragma unroll
  for (int m = 1; m < 32; m <<= 1) var += __shfl_xor(var, m);
  var *= (1.0f / DH);
  float rstd = rsqrtf(var + EPSF);

  float xn = d * rstd * ln_w[ch] + ln_b[ch];
  float g = 0.5f * xn * (1.0f + erff(xn * 0.70710678118654752f));
  float o0 = w_off[ch] * g;
  float o1 = w_off[DH + ch] * g;
#pragma unroll
  for (int m = 1; m < 32; m <<= 1) {
    o0 += __shfl_xor(o0, m);
    o1 += __shfl_xor(o1, m);
  }

  const float ref_y = (0.5f + (float)yk) / 23.0f * 2.0f - 1.0f;
  const float ref_x = (0.5f + (float)xk) / 23.0f * 2.0f - 1.0f;
  float py = fminf(fmaxf(o0 + ref_y, -1.0f), 1.0f);
  float px = fminf(fmaxf(o1 + ref_x, -1.0f), 1.0f);

  float gx = (px + 1.0f) * 0.5f * 47.0f;
  float gy = (py + 1.0f) * 0.5f * 47.0f;
  float x0f = floorf(gx), y0f = floorf(gy);
  float wx = gx - x0f, wy = gy - y0f;
  int x0 = (int)x0f, y0 = (int)y0f;
  int x0i = min(max(x0, 0), WW - 1);
  int x1i = min(max(x0 + 1, 0), WW - 1);
  int y0i = min(max(y0, 0), HH - 1);
  int y1i = min(max(y0 + 1, 0), HH - 1);
  float w00 = (1.f - wx) * (1.f - wy);
  float w01 = wx * (1.f - wy);
  float w10 = (1.f - wx) * wy;
  float w11 = wx * wy;

  const float* kvb = kvT + (size_t)b * HW * 256 + head * DH + ch;
  float val = w00 * kvb[(size_t)(y0i * WW + x0i) * 256]
            + w01 * kvb[(size_t)(y0i * WW + x1i) * 256]
            + w10 * kvb[(size_t)(y1i * WW + x0i) * 256]
            + w11 * kvb[(size_t)(y1i * WW + x1i) * 256];

  unsigned ub = __builtin_bit_cast(unsigned, val);
  unsigned uh = ub & 0xffff0000u;
  float rem = val - __builtin_bit_cast(float, uh);
  size_t idx = ((size_t)b * NN + n) * 256 + head * DH + ch;
  kvsTh[idx] = (short)(uh >> 16);
  kvsTl[idx] = (short)(__builtin_bit_cast(unsigned, rem) >> 16);
}

// ---------------------------------------------------------------------------
// Fused K/V GEMM from kvsT (b,n,256) hi/lo; W read fp32 + in-reg split8.
// K-loop W loads software-pipelined (depth-1) / fully hoisted (mode 1) to
// raise memory-level parallelism; accumulation order unchanged.
// mode = blockIdx.y>>2: 0 -> K^T (b,n,256o); 1 -> V (b,256o,n).
// Grid (9, 8, 8), 256 threads.
// ---------------------------------------------------------------------------
__global__ __launch_bounds__(256) void kv_gemm_mfma(
    const float* __restrict__ wk, const float* __restrict__ bk,
    const float* __restrict__ wv, const float* __restrict__ bv,
    const short* __restrict__ Xh, const short* __restrict__ Xl,
    short* __restrict__ Kb, short* __restrict__ Vb) {
  const int tid = threadIdx.x;
  const int wave = tid >> 6;
  const int lane = tid & 63;
  const int quad = lane >> 4, l15 = lane & 15;
  const int b = blockIdx.z;
  const int mode = blockIdx.y >> 2;
  const int oTile = (blockIdx.y & 3) * 64;
  const int nBase = blockIdx.x * 64;

  if (mode == 0) {
    const int nW = nBase + wave * 16;
    const short* arh = Xh + ((size_t)b * NN + nW + l15) * 256 + quad * 8;
    const short* arl = Xl + ((size_t)b * NN + nW + l15) * 256 + quad * 8;
    f32x4 acc[4] = {};
    // depth-1 pipelined W loads (raw fp32; split at use -- same values/order)
    float wc[4][8], wn[4][8];
#pragma unroll
    for (int ot = 0; ot < 4; ot++) {
      const float* wrow = wk + (size_t)(oTile + ot * 16 + l15) * 256 + quad * 8;
      *(float4*)(wc[ot]) = *(const float4*)(wrow);
      *(float4*)(wc[ot] + 4) = *(const float4*)(wrow + 4);
    }
#pragma unroll
    for (int kk = 0; kk < 8; kk++) {
      const int kc = kk * 32;
      if (kk < 7) {
#pragma unroll
        for (int ot = 0; ot < 4; ot++) {
          const float* wrow = wk + (size_t)(oTile + ot * 16 + l15) * 256 + kc + 32 + quad * 8;
          *(float4*)(wn[ot]) = *(const float4*)(wrow);
          *(float4*)(wn[ot] + 4) = *(const float4*)(wrow + 4);
        }
      }
      short8 ah = *(const short8*)(arh + kc);
      short8 al = *(const short8*)(arl + kc);
#pragma unroll
      for (int ot = 0; ot < 4; ot++) {
        short8 bh_, bl_;
        split8(wc[ot], bh_, bl_);
        acc[ot] = __builtin_amdgcn_mfma_f32_16x16x32_bf16(ah, bh_, acc[ot], 0, 0, 0);
        acc[ot] = __builtin_amdgcn_mfma_f32_16x16x32_bf16(al, bh_, acc[ot], 0, 0, 0);
        acc[ot] = __builtin_amdgcn_mfma_f32_16x16x32_bf16(ah, bl_, acc[ot], 0, 0, 0);
      }
      if (kk < 7) {
#pragma unroll
        for (int ot = 0; ot < 4; ot++)
#pragma unroll
          for (int j = 0; j < 8; j++) wc[ot][j] = wn[ot][j];
      }
    }
    float bs[4];
#pragma unroll
    for (int ot = 0; ot < 4; ot++) bs[ot] = bk[oTile + ot * 16 + l15];
#pragma unroll
    for (int r = 0; r < 4; r++) {
      short* yp = Kb + ((size_t)b * NN + nW + quad * 4 + r) * 256 + oTile + l15;
#pragma unroll
      for (int ot = 0; ot < 4; ot++) yp[ot * 16] = f2bf_s(acc[ot][r] + bs[ot]);
    }
  } else {
    const int oW = oTile + wave * 16;
    const float* wrow = wv + (size_t)(oW + l15) * 256 + quad * 8;
    // hoist the entire 64-float W row (16 float4 loads in flight at once)
    float wreg[64];
#pragma unroll
    for (int kk = 0; kk < 8; kk++) {
      *(float4*)(wreg + kk * 8) = *(const float4*)(wrow + kk * 32);
      *(float4*)(wreg + kk * 8 + 4) = *(const float4*)(wrow + kk * 32 + 4);
    }
    f32x4 acc[4] = {};
#pragma unroll
    for (int kk = 0; kk < 8; kk++) {
      const int kc = kk * 32;
      short8 ah, al;
      split8(wreg + kk * 8, ah, al);
#pragma unroll
      for (int nt = 0; nt < 4; nt++) {
        short8 bh_ = *(const short8*)(Xh + ((size_t)b * NN + nBase + nt * 16 + l15) * 256 + kc + quad * 8);
        short8 bl_ = *(const short8*)(Xl + ((size_t)b * NN + nBase + nt * 16 + l15) * 256 + kc + quad * 8);
        acc[nt] = __builtin_amdgcn_mfma_f32_16x16x32_bf16(ah, bh_, acc[nt], 0, 0, 0);
        acc[nt] = __builtin_amdgcn_mfma_f32_16x16x32_bf16(al, bh_, acc[nt], 0, 0, 0);
        acc[nt] = __builtin_amdgcn_mfma_f32_16x16x32_bf16(ah, bl_, acc[nt], 0, 0, 0);
      }
    }
#pragma unroll
    for (int r = 0; r < 4; r++) {
      int o = oW + quad * 4 + r;
      float bs = bv[o];
      short* yp = Vb + ((size_t)b * 256 + o) * NN + nBase + l15;
#pragma unroll
      for (int nt = 0; nt < 4; nt++) yp[nt * 16] = f2bf_s(acc[nt][r] + bs);
    }
  }
}

// ---------------------------------------------------------------------------
// MFMA attention v7 (round-5 form, best measured): block-cooperative K/V LDS
// staging (double-buffered, 1 barrier/stage), mt=2 per wave, fixed-swizzle P
// transpose, denominator via ones-MFMA. Grid (18, 64), 256 threads.
// ---------------------------------------------------------------------------
__global__ __launch_bounds__(256) void attn_mfma(const float* __restrict__ q,
                                                 const short* __restrict__ Kb,
                                                 const short* __restrict__ Vb,
                                                 short* __restrict__ O) {
  __shared__ short sK[2][64 * 40];    // row stride 40 shorts (80 B)
  __shared__ short sV[2][32 * 88];    // row stride 88 shorts (176 B)
  __shared__ int sP[4][2][256];       // per-wave P transpose buffers
  const int tid = threadIdx.x;
  const int wave = tid >> 6;
  const int lane = tid & 63;
  const int quad = lane >> 4;
  const int l15 = lane & 15;
  const int bh = blockIdx.y;
  const int b = bh >> 3, head = bh & 7;
  const int mBase = blockIdx.x * 128 + wave * 32;

  short8 bq[2];
#pragma unroll
  for (int mt = 0; mt < 2; mt++) {
    const float* qp = q + ((size_t)bh * DH + quad * 8) * HW + mBase + mt * 16 + l15;
    short8 v;
#pragma unroll
    for (int j = 0; j < 8; j++) v[j] = f2bf_s(qp[(size_t)j * HW] * SCALE);
    bq[mt] = v;
  }

  const int kn = tid >> 2, kc = (tid & 3) * 8;
  const int vc = tid >> 3, vn = (tid & 7) * 8;
  const short* kg = Kb + (size_t)b * NN * 256 + head * DH;
  const short* vg = Vb + ((size_t)b * 256 + head * DH) * NN;

  short8 kreg = *(const short8*)(kg + (size_t)kn * 256 + kc);
  short8 vreg = *(const short8*)(vg + (size_t)vc * NN + vn);
  *(short8*)(&sK[0][kn * 40 + kc]) = kreg;
  *(short8*)(&sV[0][vc * 88 + vn]) = vreg;
  __syncthreads();

  const int g = (l15 >> 1) & 3;
  const int row16 = l15 * 16;
  const int wr0 = row16 + (((quad >> 1) ^ g) << 2) + ((quad & 1) << 1);
  const int wr1 = row16 + (((2 + (quad >> 1)) ^ g) << 2) + ((quad & 1) << 1);
  const int rd = row16 + ((quad ^ g) << 2);

  f32x4 oacc[2][2] = {};
  f32x4 dacc[2] = {};
  const short ONE = 0x3F80;
  const short8 ones = {ONE, ONE, ONE, ONE, ONE, ONE, ONE, ONE};

  for (int s = 0; s < 9; s++) {
    const int buf = s & 1;
    if (s + 1 < 9) {
      kreg = *(const short8*)(kg + (size_t)((s + 1) * 64 + kn) * 256 + kc);
      vreg = *(const short8*)(vg + (size_t)vc * NN + (s + 1) * 64 + vn);
    }
#pragma unroll
    for (int nt = 0; nt < 2; nt++) {
      short8 ka0 = *(const short8*)(&sK[buf][(nt * 32 + l15) * 40 + quad * 8]);
      short8 ka1 = *(const short8*)(&sK[buf][(nt * 32 + 16 + l15) * 40 + quad * 8]);
      short8 va0 = *(const short8*)(&sV[buf][l15 * 88 + nt * 32 + quad * 8]);
      short8 va1 = *(const short8*)(&sV[buf][(16 + l15) * 88 + nt * 32 + quad * 8]);
      f32x4 z = {0.f, 0.f, 0.f, 0.f};
      f32x4 st[2][2];
      st[0][0] = __builtin_amdgcn_mfma_f32_16x16x32_bf16(ka0, bq[0], z, 0, 0, 0);
      st[0][1] = __builtin_amdgcn_mfma_f32_16x16x32_bf16(ka1, bq[0], z, 0, 0, 0);
      st[1][0] = __builtin_amdgcn_mfma_f32_16x16x32_bf16(ka0, bq[1], z, 0, 0, 0);
      st[1][1] = __builtin_amdgcn_mfma_f32_16x16x32_bf16(ka1, bq[1], z, 0, 0, 0);
#pragma unroll
      for (int mt = 0; mt < 2; mt++) {
        float p0 = __expf(st[mt][0][0]), p1 = __expf(st[mt][0][1]);
        float p2 = __expf(st[mt][0][2]), p3 = __expf(st[mt][0][3]);
        float p4 = __expf(st[mt][1][0]), p5 = __expf(st[mt][1][1]);
        float p6 = __expf(st[mt][1][2]), p7 = __expf(st[mt][1][3]);
        int* base = &sP[wave][mt][0];
        *(int2*)(base + wr0) = make_int2((int)pkrnd(p0, p1), (int)pkrnd(p2, p3));
        *(int2*)(base + wr1) = make_int2((int)pkrnd(p4, p5), (int)pkrnd(p6, p7));
      }
#pragma unroll
      for (int mt = 0; mt < 2; mt++) {
        short8 pa = *(short8*)(&sP[wave][mt][0] + rd);
        oacc[mt][0] = __builtin_amdgcn_mfma_f32_16x16x32_bf16(pa, va0, oacc[mt][0], 0, 0, 0);
        oacc[mt][1] = __builtin_amdgcn_mfma_f32_16x16x32_bf16(pa, va1, oacc[mt][1], 0, 0, 0);
        dacc[mt] = __builtin_amdgcn_mfma_f32_16x16x32_bf16(pa, ones, dacc[mt], 0, 0, 0);
      }
    }
    if (s + 1 < 9) {
      *(short8*)(&sK[buf ^ 1][kn * 40 + kc]) = kreg;
      *(short8*)(&sV[buf ^ 1][vc * 88 + vn]) = vreg;
    }
    __syncthreads();
  }

#pragma unroll
  for (int mt = 0; mt < 2; mt++) {
    short* ob = O + ((size_t)b * HW + mBase + mt * 16) * 256 + head * DH + l15;
#pragma unroll
    for (int r = 0; r < 4; r++) {
      float inv = 1.0f / dacc[mt][r];
      ob[(size_t)(quad * 4 + r) * 256] = f2bf_s(oacc[mt][0][r] * inv);
      ob[(size_t)(quad * 4 + r) * 256 + 16] = f2bf_s(oacc[mt][1][r] * inv);
    }
  }
}

// ---------------------------------------------------------------------------
// wo GEMM (round-5 form + depth-1 W pipeline): 512 threads, 8 waves x
// (32o x 64m), X tile staged in 32KB LDS (chunk-XOR swizzle); W read fp32 +
// in-reg split8. Grid (36, 8). Accumulation order unchanged.
// ---------------------------------------------------------------------------
__global__ __launch_bounds__(512) void wo_gemm_mfma(const float* __restrict__ wo,
                                                    const float* __restrict__ bias,
                                                    const short* __restrict__ X,
                                                    float* __restrict__ Y) {
  __shared__ short sX[64 * 256];   // 32 KB
  const int tid = threadIdx.x;
  const int b = blockIdx.y;
  const int mBase = blockIdx.x * 64;

  const short* src = X + ((size_t)b * HW + mBase) * 256;
#pragma unroll
  for (int it = 0; it < 4; it++) {
    int idx = it * 512 + tid;        // 0..2047
    int row = idx >> 5, ck = idx & 31;
    *(short8*)(&sX[row * 256 + ((ck ^ (row & 7)) << 3)]) =
        *(const short8*)(src + (size_t)row * 256 + ck * 8);
  }
  __syncthreads();

  const int wave = tid >> 6, lane = tid & 63;
  const int quad = lane >> 4, l15 = lane & 15;
  const int oBase = wave * 32;

  f32x4 acc[2][4] = {};
  float wc[2][8], wn[2][8];
#pragma unroll
  for (int os = 0; os < 2; os++) {
    const float* wrow = wo + (size_t)(oBase + os * 16 + l15) * 256 + quad * 8;
    *(float4*)(wc[os]) = *(const float4*)(wrow);
    *(float4*)(wc[os] + 4) = *(const float4*)(wrow + 4);
  }
#pragma unroll
  for (int kk = 0; kk < 8; kk++) {
    const int kc = kk * 32;
    if (kk < 7) {
#pragma unroll
      for (int os = 0; os < 2; os++) {
        const float* wrow = wo + (size_t)(oBase + os * 16 + l15) * 256 + kc + 32 + quad * 8;
        *(float4*)(wn[os]) = *(const float4*)(wrow);
        *(float4*)(wn[os] + 4) = *(const float4*)(wrow + 4);
      }
    }
    short8 ah[2], al[2];
    split8(wc[0], ah[0], al[0]);
    split8(wc[1], ah[1], al[1]);
#pragma unroll
    for (int mt = 0; mt < 4; mt++) {
      int row = mt * 16 + l15;
      short8 bx = *(const short8*)(&sX[row * 256 + ((((kc >> 3) + quad) ^ (row & 7)) << 3)]);
#pragma unroll
      for (int os = 0; os < 2; os++) {
        acc[os][mt] = __builtin_amdgcn_mfma_f32_16x16x32_bf16(ah[os], bx, acc[os][mt], 0, 0, 0);
        acc[os][mt] = __builtin_amdgcn_mfma_f32_16x16x32_bf16(al[os], bx, acc[os][mt], 0, 0, 0);
      }
    }
    if (kk < 7) {
#pragma unroll
      for (int os = 0; os < 2; os++)
#pragma unroll
        for (int j = 0; j < 8; j++) wc[os][j] = wn[os][j];
    }
  }

#pragma unroll
  for (int os = 0; os < 2; os++)
#pragma unroll
    for (int r = 0; r < 4; r++) {
      int o = oBase + os * 16 + quad * 4 + r;
      float bs = bias[o];
      float* yp = Y + ((size_t)b * 256 + o) * HW + mBase + l15;
#pragma unroll
      for (int mt = 0; mt < 4; mt++) yp[mt * 16] = acc[os][mt][r] + bs;
    }
}

// ---------------------------------------------------------------------------
extern "C" void kernel_launch(void* const* d_in, const int* in_sizes, int n_in,
                              void* d_out, int out_size, void* d_ws, size_t ws_size,
                              hipStream_t stream) {
  const float* x    = (const float*)d_in[0];
  const float* kv   = (const float*)d_in[1];
  const float* wq   = (const float*)d_in[2];
  const float* bq   = (const float*)d_in[3];
  const float* wk   = (const float*)d_in[4];
  const float* bk   = (const float*)d_in[5];
  const float* wv   = (const float*)d_in[6];
  const float* bv   = (const float*)d_in[7];
  const float* w_dw = (const float*)d_in[8];
  const float* b_dw = (const float*)d_in[9];
  const float* ln_w = (const float*)d_in[10];
  const float* ln_b = (const float*)d_in[11];
  const float* w_off= (const float*)d_in[12];
  const float* wo   = (const float*)d_in[13];
  const float* bo   = (const float*)d_in[14];
  float* out = (float*)d_out;
  float* ws = (float*)d_ws;

  // workspace (float slots), lifetimes:
  //   q     [0,        4718592)  fp32, born gemm_q, read by dw_sample + attn
  //   O     [4718592,  7077888)  bf16, born attn, read by wo
  //   kvsTh [7077888,  7667712), kvsTl [7667712, 8257536)  born dw
  //   Kb    [8257536,  8847360), Vb    [8847360, 9437184)  born kv_gemm
  // kvT (fp32, (b,hw,256)) lives in d_out: written by gemm_q_fused's
  // transpose blocks, read by dw_sample, overwritten at the end by wo_gemm.
  float* q     = ws;
  short* O     = (short*)(ws + 4718592);
  short* kvsTh = (short*)(ws + 7077888);
  short* kvsTl = (short*)(ws + 7667712);
  short* Kb    = (short*)(ws + 8257536);
  short* Vb    = (short*)(ws + 8847360);
  float* kvT = out;

  gemm_q_fused<<<dim3(1440), dim3(512), 0, stream>>>(wq, bq, x, q, kv, kvT);
  dw_sample_kernel<<<dim3(BH * NN / 8), dim3(256), 0, stream>>>(
      q, kvT, w_dw, b_dw, ln_w, ln_b, w_off, kvsTh, kvsTl);
  kv_gemm_mfma<<<dim3(NN / 64, 8, BB), dim3(256), 0, stream>>>(
      wk, bk, wv, bv, kvsTh, kvsTl, Kb, Vb);
  attn_mfma<<<dim3(HW / 128, BH), dim3(256), 0, stream>>>(q, Kb, Vb, O);
  wo_gemm_mfma<<<dim3(HW / 64, BB), dim3(512), 0, stream>>>(wo, bo, O, out);
}